// Round 5
// baseline (578.278 us; speedup 1.0000x reference)
//
#include <hip/hip_runtime.h>
#include <hip/hip_bf16.h>
#include <cstdint>
#include <cmath>

#define NEG_SLOPE 0.2f

static __device__ __forceinline__ float leaky(float x){ return x >= 0.f ? x : NEG_SLOPE*x; }

// ---------------- histogram of segment sizes (atomics only) ----------------
__global__ __launch_bounds__(256) void hist_k(const int* __restrict__ edges, const int* __restrict__ vertex,
                                              int* __restrict__ ce, int* __restrict__ cv, int nnz){
  int i = blockIdx.x*256 + threadIdx.x;
  if (i < nnz){ atomicAdd(&ce[edges[i]], 1); atomicAdd(&cv[vertex[i]], 1); }
}

// ---------------- 3-pass exclusive scan (both arrays via blockIdx.y) ----------------
__global__ __launch_bounds__(256) void scan_reduce_k(const int* __restrict__ ce, const int* __restrict__ cv,
                                                     int M, int N, int* __restrict__ partials){
  const int* src = blockIdx.y ? cv : ce;
  const int L = blockIdx.y ? N : M;
  const int base = blockIdx.x*2048;
  int s = 0;
  for (int j = threadIdx.x; j < 2048; j += 256){
    int idx = base + j;
    if (idx < L) s += src[idx];
  }
  for (int o = 32; o > 0; o >>= 1) s += __shfl_down(s, o);
  __shared__ int wsum[4];
  if ((threadIdx.x & 63) == 0) wsum[threadIdx.x >> 6] = s;
  __syncthreads();
  if (threadIdx.x == 0) partials[blockIdx.y*64 + blockIdx.x] = wsum[0]+wsum[1]+wsum[2]+wsum[3];
}

__global__ __launch_bounds__(128) void scan_partials_k(int* __restrict__ partials){
  const int w = threadIdx.x >> 6, l = threadIdx.x & 63;
  int v = partials[w*64 + l];
  int inc = v;
  for (int o = 1; o < 64; o <<= 1){ int u = __shfl_up(inc, o); if (l >= o) inc += u; }
  partials[w*64 + l] = inc - v;   // exclusive
}

// writes offsets AND re-initializes the counts array as the placement cursor
__global__ __launch_bounds__(256) void scan_write_k(int* __restrict__ ce, int* __restrict__ cv,
                                                    int M, int N, const int* __restrict__ partials,
                                                    int* __restrict__ e_off, int* __restrict__ v_off){
  int* src; int L; int* off;
  if (blockIdx.y == 0){ src = ce; L = M; off = e_off; }
  else                { src = cv; L = N; off = v_off; }
  const int base = blockIdx.x*2048 + threadIdx.x*8;
  int v[8];
  int tot = 0;
  #pragma unroll
  for (int j = 0; j < 8; ++j){ int idx = base+j; v[j] = (idx < L) ? src[idx] : 0; tot += v[j]; }
  const int lane = threadIdx.x & 63, wid = threadIdx.x >> 6;
  int inc = tot;
  for (int o = 1; o < 64; o <<= 1){ int u = __shfl_up(inc, o); if (lane >= o) inc += u; }
  __shared__ int wsum[4];
  if (lane == 63) wsum[wid] = inc;
  __syncthreads();
  int wbase = 0;
  for (int k = 0; k < wid; ++k) wbase += wsum[k];
  int run = partials[blockIdx.y*64 + blockIdx.x] + wbase + inc - tot;
  #pragma unroll
  for (int j = 0; j < 8; ++j){
    int idx = base + j;
    if (idx < L){
      off[idx] = run;
      src[idx] = run;       // cursor for place_k
      run += v[j];
      if (idx == L-1) off[L] = run;
    }
  }
}

// ---------------- single-pass placement: cursor atomicAdd + coherent-point store -------
__global__ __launch_bounds__(256) void place_k(const int* __restrict__ edges, const int* __restrict__ vertex,
                                               int* __restrict__ e_cur, int* __restrict__ v_cur,
                                               int* __restrict__ e_ent, int* __restrict__ v_ent, int nnz){
  int i = blockIdx.x*256 + threadIdx.x;
  if (i < nnz){
    int p = atomicAdd(&e_cur[edges[i]], 1);
    atomicExch(&e_ent[p], i);
    int q = atomicAdd(&v_cur[vertex[i]], 1);
    atomicExch(&v_ent[q], i);
  }
}

// ---------------- X0 = X @ W + b  with fused per-node attention scores ----------------
// 64 rows/block, 512 threads. Thread (tr,tc) owns rows {tr*2, tr*2+1} and cols
// {tc*4..tc*4+3} U {64+tc*4..64+tc*4+3}  (consecutive float4 per 16-lane group ->
// conflict-free ds_read_b128; old tc*8 layout was a 4-way bank conflict, 1.33e7/dispatch).
__global__ __launch_bounds__(512) void gemm_k(const float* __restrict__ X, const float* __restrict__ W,
                                              const float* __restrict__ bias, const float* __restrict__ att_e,
                                              float* __restrict__ Y, float* __restrict__ sc_n, int N){
  __shared__ float Bs[64*128];   // k-half x all cols (32 KB)
  __shared__ float As[64*65];    // rows x k-half, +1 pad (16.25 KB)
  __shared__ float att_s[128];
  const int t = threadIdx.x;
  if (t < 128) att_s[t] = att_e[t];
  const int row0 = blockIdx.x * 64;
  const int tr = t >> 4, tc = t & 15;       // tr 0..31, tc 0..15
  const int r = tr*2;
  const int cA = tc*4, cB = 64 + tc*4;
  float acc[2][8];                          // [row][0..3]=cA cols, [4..7]=cB cols
  {
    float4 b0 = ((const float4*)bias)[tc];
    float4 b1 = ((const float4*)bias)[16 + tc];
    acc[0][0]=b0.x; acc[0][1]=b0.y; acc[0][2]=b0.z; acc[0][3]=b0.w;
    acc[0][4]=b1.x; acc[0][5]=b1.y; acc[0][6]=b1.z; acc[0][7]=b1.w;
    #pragma unroll
    for (int j = 0; j < 8; ++j) acc[1][j] = acc[0][j];
  }
  for (int kh = 0; kh < 2; ++kh){
    {
      const float4* W4 = (const float4*)(W + kh*64*128);
      float4* B4 = (float4*)Bs;
      #pragma unroll
      for (int j = 0; j < 4; ++j) B4[j*512 + t] = W4[j*512 + t];
      #pragma unroll
      for (int j = 0; j < 2; ++j){
        int idx = j*512 + t;
        int rr = idx >> 4, c4 = idx & 15;
        int gr = row0 + rr;
        float4 v = make_float4(0.f,0.f,0.f,0.f);
        if (gr < N) v = ((const float4*)X)[(size_t)gr*32 + kh*16 + c4];
        float* dst = &As[rr*65 + c4*4];
        dst[0]=v.x; dst[1]=v.y; dst[2]=v.z; dst[3]=v.w;
      }
    }
    __syncthreads();
    #pragma unroll 4
    for (int k = 0; k < 64; ++k){
      float a0 = As[r*65 + k], a1 = As[(r+1)*65 + k];
      const float4 w0 = *(const float4*)&Bs[k*128 + cA];
      const float4 w1 = *(const float4*)&Bs[k*128 + cB];
      float wv[8] = {w0.x,w0.y,w0.z,w0.w,w1.x,w1.y,w1.z,w1.w};
      #pragma unroll
      for (int j = 0; j < 8; ++j){ acc[0][j] += a0*wv[j]; acc[1][j] += a1*wv[j]; }
    }
    __syncthreads();
  }
  // fused node scores. cols cA..cA+3 belong to head tc>>2; cB cols to head (tc>>2)+4.
  // att flat index for col c is just c (h*16 + c%16 == c).
  float pA0=0.f, pA1=0.f, pB0=0.f, pB1=0.f;
  #pragma unroll
  for (int j = 0; j < 4; ++j){
    float aa = att_s[cA + j], ab = att_s[cB + j];
    pA0 += acc[0][j]*aa;   pA1 += acc[1][j]*aa;
    pB0 += acc[0][4+j]*ab; pB1 += acc[1][4+j]*ab;
  }
  #pragma unroll
  for (int o = 1; o < 4; o <<= 1){
    pA0 += __shfl_xor(pA0, o); pA1 += __shfl_xor(pA1, o);
    pB0 += __shfl_xor(pB0, o); pB1 += __shfl_xor(pB1, o);
  }
  #pragma unroll
  for (int i = 0; i < 2; ++i){
    int gr = row0 + r + i;
    if (gr < N){
      float4 o0 = make_float4(acc[i][0],acc[i][1],acc[i][2],acc[i][3]);
      float4 o1 = make_float4(acc[i][4],acc[i][5],acc[i][6],acc[i][7]);
      float4* Y4 = (float4*)Y;
      Y4[(size_t)gr*32 + tc]      = o0;
      Y4[(size_t)gr*32 + 16 + tc] = o1;
    }
  }
  if ((tc & 3) == 0){
    int h = tc >> 2;
    int g0 = row0 + r, g1 = row0 + r + 1;
    if (g0 < N){ sc_n[(size_t)g0*8 + h] = leaky(pA0); sc_n[(size_t)g0*8 + 4 + h] = leaky(pB0); }
    if (g1 < N){ sc_n[(size_t)g1*8 + h] = leaky(pA1); sc_n[(size_t)g1*8 + 4 + h] = leaky(pB1); }
  }
}

// ---------------- segment softmax + weighted segment-sum (one wave per segment) --------
// STAGE1: src fp32 (X0), out bf16 (Xe) + relu + fused per-edge scores (fp32, from exact
//         fp32 aggregate -> stage-2 weights are unpolluted by the bf16 value rounding).
// STAGE2: src bf16 (Xe), out fp32 (d_out).
template<bool STAGE1>
__global__ __launch_bounds__(256) void agg_k(const void* __restrict__ src_, const int* __restrict__ map,
                                             const float* __restrict__ sctab, const int* __restrict__ seg_off,
                                             const int* __restrict__ seg_ent, const float* __restrict__ att2,
                                             void* __restrict__ out_, float* __restrict__ sc_out, int nseg){
  __shared__ float s_lds[4][128][8];
  __shared__ int   r_lds[4][128];
  __shared__ float m_lds[4][8];
  __shared__ float d_lds[4][8];
  __shared__ float att_s[128];
  const float* srcf = (const float*)src_;
  const __hip_bfloat16* srcb = (const __hip_bfloat16*)src_;
  const int wid = threadIdx.x >> 6, lane = threadIdx.x & 63;
  if (STAGE1 && threadIdx.x < 128) att_s[threadIdx.x] = att2[threadIdx.x];
  const int seg = blockIdx.x*4 + wid;
  const bool active = seg < nseg;
  int start = 0, cnt = 0;
  if (active){ start = seg_off[seg]; cnt = seg_off[seg+1] - start; }
  const bool fits = (cnt <= 128);

  // phase 1: stage per-entry head scores (gathered from the per-row table) + row ids
  if (active && fits){
    for (int j = lane; j < cnt; j += 64){
      int id = seg_ent[start + j];
      int row = map[id];
      r_lds[wid][j] = row;
      const float4* sp = (const float4*)(sctab + (size_t)row*8);
      float4 x0 = sp[0], x1 = sp[1];
      float* dst = &s_lds[wid][j][0];
      ((float4*)dst)[0] = x0;
      ((float4*)dst)[1] = x1;
    }
  }
  __syncthreads();
  // phase 2: wave-parallel per-head max & sum. lane = jj*8 + h
  if (active && fits){
    const int h = lane & 7, jj = lane >> 3;
    float m = -INFINITY;
    for (int j = jj; j < cnt; j += 8) m = fmaxf(m, s_lds[wid][j][h]);
    #pragma unroll
    for (int o = 8; o < 64; o <<= 1) m = fmaxf(m, __shfl_xor(m, o));
    float s = 0.f;
    for (int j = jj; j < cnt; j += 8) s += __expf(s_lds[wid][j][h] - m);
    #pragma unroll
    for (int o = 8; o < 64; o <<= 1) s += __shfl_xor(s, o);
    if (lane < 8){ m_lds[wid][lane] = m; d_lds[wid][lane] = 1.f / (s + 1e-16f); }
  }
  __syncthreads();
  // phase 2b: scores -> softmax weights in place
  if (active && fits){
    for (int idx = lane; idx < cnt*8; idx += 64){
      int j = idx >> 3, h = idx & 7;
      s_lds[wid][j][h] = __expf(s_lds[wid][j][h] - m_lds[wid][h]) * d_lds[wid][h];
    }
  }
  __syncthreads();
  // phase 3: weighted sum of gathered rows; lane covers cols (lane, lane+64)
  if (active){
    float acc0 = 0.f, acc1 = 0.f;
    const int ha = lane >> 4, hb = ha + 4;
    if (fits){
      for (int j = 0; j < cnt; ++j){
        float wa = s_lds[wid][j][ha];
        float wb = s_lds[wid][j][hb];
        float x0, x1;
        if (STAGE1){
          const float* xr = srcf + (size_t)r_lds[wid][j]*128;
          x0 = xr[lane]; x1 = xr[lane + 64];
        } else {
          const __hip_bfloat16* xr = srcb + (size_t)r_lds[wid][j]*128;
          x0 = __bfloat162float(xr[lane]); x1 = __bfloat162float(xr[lane + 64]);
        }
        acc0 += wa * x0;
        acc1 += wb * x1;
      }
    } else {
      // overflow fallback (cnt > 128): 3-pass from global; essentially never taken
      float ma = -INFINITY, mb = -INFINITY;
      for (int j = 0; j < cnt; ++j){
        int id = seg_ent[start + j];
        int row = map[id];
        ma = fmaxf(ma, sctab[(size_t)row*8 + ha]);
        mb = fmaxf(mb, sctab[(size_t)row*8 + hb]);
      }
      float sa = 0.f, sb = 0.f;
      for (int j = 0; j < cnt; ++j){
        int id = seg_ent[start + j];
        int row = map[id];
        sa += __expf(sctab[(size_t)row*8 + ha] - ma);
        sb += __expf(sctab[(size_t)row*8 + hb] - mb);
      }
      float ra = 1.f/(sa + 1e-16f), rb = 1.f/(sb + 1e-16f);
      for (int j = 0; j < cnt; ++j){
        int id = seg_ent[start + j];
        int row = map[id];
        float wa = __expf(sctab[(size_t)row*8 + ha] - ma) * ra;
        float wb = __expf(sctab[(size_t)row*8 + hb] - mb) * rb;
        float x0, x1;
        if (STAGE1){
          const float* xr = srcf + (size_t)row*128;
          x0 = xr[lane]; x1 = xr[lane + 64];
        } else {
          const __hip_bfloat16* xr = srcb + (size_t)row*128;
          x0 = __bfloat162float(xr[lane]); x1 = __bfloat162float(xr[lane + 64]);
        }
        acc0 += wa * x0;
        acc1 += wb * x1;
      }
    }
    if (STAGE1){
      float o0 = fmaxf(acc0, 0.f);
      float o1 = fmaxf(acc1, 0.f);
      __hip_bfloat16* outb = (__hip_bfloat16*)out_;
      outb[(size_t)seg*128 + lane]      = __float2bfloat16(o0);
      outb[(size_t)seg*128 + 64 + lane] = __float2bfloat16(o1);
      // fused per-segment (edge) scores for stage 2, from the EXACT fp32 aggregate
      float p0 = o0 * att_s[lane];        // att2[ha*16 + (lane&15)] == att2[lane]
      float p1 = o1 * att_s[lane + 64];   // att2[(ha+4)*16 + (lane&15)] == att2[lane+64]
      #pragma unroll
      for (int o = 1; o < 16; o <<= 1){ p0 += __shfl_xor(p0, o); p1 += __shfl_xor(p1, o); }
      if ((lane & 15) == 0){
        sc_out[(size_t)seg*8 + (lane >> 4)]     = leaky(p0);
        sc_out[(size_t)seg*8 + 4 + (lane >> 4)] = leaky(p1);
      }
    } else {
      float* outf = (float*)out_;
      outf[(size_t)seg*128 + lane]      = acc0;
      outf[(size_t)seg*128 + 64 + lane] = acc1;
    }
  }
}

extern "C" void kernel_launch(void* const* d_in, const int* in_sizes, int n_in,
                              void* d_out, int out_size, void* d_ws, size_t ws_size,
                              hipStream_t stream){
  const float* X      = (const float*)d_in[0];
  const int*   vertex = (const int*)d_in[1];
  const int*   edges  = (const int*)d_in[2];
  const float* W_w    = (const float*)d_in[3];
  const float* W_b    = (const float*)d_in[4];
  const float* att_e  = (const float*)d_in[5];
  const float* att_v  = (const float*)d_in[6];
  const int N   = in_sizes[0] / 128;   // 100000
  const int NNZ = in_sizes[1];         // 800000
  const int M   = 50000;               // edge_num (fixed problem size)

  char* p = (char*)d_ws;
  auto take = [&](size_t bytes)->void*{
    void* q = (void*)p;
    p += (bytes + 255) & ~(size_t)255;
    return q;
  };
  float* X0        = (float*)take((size_t)N*128*sizeof(float));          // 51.2 MB
  __hip_bfloat16* Xe = (__hip_bfloat16*)take((size_t)M*128*sizeof(__hip_bfloat16)); // 12.8 MB
  float* sc_n      = (float*)take((size_t)N*8*sizeof(float));            // 3.2 MB
  float* sc_e      = (float*)take((size_t)M*8*sizeof(float));            // 1.6 MB
  int*   e_off     = (int*)take((size_t)(M+1)*sizeof(int));
  int*   v_off     = (int*)take((size_t)(N+1)*sizeof(int));
  int*   e_cnt     = (int*)take((size_t)M*sizeof(int));                  // counts, then cursors
  int*   v_cnt     = (int*)take((size_t)N*sizeof(int));
  int*   e_ent     = (int*)take((size_t)NNZ*sizeof(int));
  int*   v_ent     = (int*)take((size_t)NNZ*sizeof(int));
  int*   partials  = (int*)take(128*sizeof(int));

  hipMemsetAsync(e_cnt, 0, (size_t)M*sizeof(int), stream);
  hipMemsetAsync(v_cnt, 0, (size_t)N*sizeof(int), stream);

  gemm_k<<<dim3((N+63)/64), 512, 0, stream>>>(X, W_w, W_b, att_e, X0, sc_n, N);

  hist_k<<<dim3((NNZ+255)/256), 256, 0, stream>>>(edges, vertex, e_cnt, v_cnt, NNZ);
  const int LMAX = (N > M) ? N : M;
  const int nb = (LMAX + 2047)/2048;        // <= 64
  scan_reduce_k<<<dim3(nb,2), 256, 0, stream>>>(e_cnt, v_cnt, M, N, partials);
  scan_partials_k<<<dim3(1), 128, 0, stream>>>(partials);
  scan_write_k<<<dim3(nb,2), 256, 0, stream>>>(e_cnt, v_cnt, M, N, partials, e_off, v_off);
  place_k<<<dim3((NNZ+255)/256), 256, 0, stream>>>(edges, vertex, e_cnt, v_cnt, e_ent, v_ent, NNZ);

  // stage 1: per-hyperedge attention (+ fused edge scores for stage 2, bf16 Xe out)
  agg_k<true><<<dim3((M+3)/4), 256, 0, stream>>>(X0, vertex, sc_n, e_off, e_ent, att_v, Xe, sc_e, M);

  // stage 2: per-vertex attention (bf16 Xe gather, fp32 out)
  agg_k<false><<<dim3((N+3)/4), 256, 0, stream>>>(Xe, edges, sc_e, v_off, v_ent, nullptr, d_out, nullptr, N);
}

// Round 7
// 496.618 us; speedup vs baseline: 1.1644x; 1.1644x over previous
//
#include <hip/hip_runtime.h>
#include <hip/hip_bf16.h>
#include <cstdint>
#include <cmath>

#define NEG_SLOPE 0.2f

static __device__ __forceinline__ float leaky(float x){ return x >= 0.f ? x : NEG_SLOPE*x; }

// ---------------- histogram + rank (rank = arrival order within segment) ----------------
// Coalesced rank writes; atomics are the only scattered traffic here.
__global__ __launch_bounds__(256) void hist_rank_k(const int* __restrict__ edges, const int* __restrict__ vertex,
                                                   int* __restrict__ ce, int* __restrict__ cv,
                                                   int* __restrict__ re, int* __restrict__ rv, int nnz){
  int i = blockIdx.x*256 + threadIdx.x;
  if (i < nnz){
    re[i] = atomicAdd(&ce[edges[i]], 1);
    rv[i] = atomicAdd(&cv[vertex[i]], 1);
  }
}

// ---------------- 3-pass exclusive scan (both arrays via blockIdx.y) ----------------
__global__ __launch_bounds__(256) void scan_reduce_k(const int* __restrict__ ce, const int* __restrict__ cv,
                                                     int M, int N, int* __restrict__ partials){
  const int* src = blockIdx.y ? cv : ce;
  const int L = blockIdx.y ? N : M;
  const int base = blockIdx.x*2048;
  int s = 0;
  for (int j = threadIdx.x; j < 2048; j += 256){
    int idx = base + j;
    if (idx < L) s += src[idx];
  }
  for (int o = 32; o > 0; o >>= 1) s += __shfl_down(s, o);
  __shared__ int wsum[4];
  if ((threadIdx.x & 63) == 0) wsum[threadIdx.x >> 6] = s;
  __syncthreads();
  if (threadIdx.x == 0) partials[blockIdx.y*64 + blockIdx.x] = wsum[0]+wsum[1]+wsum[2]+wsum[3];
}

__global__ __launch_bounds__(128) void scan_partials_k(int* __restrict__ partials){
  const int w = threadIdx.x >> 6, l = threadIdx.x & 63;
  int v = partials[w*64 + l];
  int inc = v;
  for (int o = 1; o < 64; o <<= 1){ int u = __shfl_up(inc, o); if (l >= o) inc += u; }
  partials[w*64 + l] = inc - v;   // exclusive
}

__global__ __launch_bounds__(256) void scan_write_k(const int* __restrict__ ce, const int* __restrict__ cv,
                                                    int M, int N, const int* __restrict__ partials,
                                                    int* __restrict__ e_off, int* __restrict__ v_off){
  const int* src; int L; int* off;
  if (blockIdx.y == 0){ src = ce; L = M; off = e_off; }
  else                { src = cv; L = N; off = v_off; }
  const int base = blockIdx.x*2048 + threadIdx.x*8;
  int v[8];
  int tot = 0;
  #pragma unroll
  for (int j = 0; j < 8; ++j){ int idx = base+j; v[j] = (idx < L) ? src[idx] : 0; tot += v[j]; }
  const int lane = threadIdx.x & 63, wid = threadIdx.x >> 6;
  int inc = tot;
  for (int o = 1; o < 64; o <<= 1){ int u = __shfl_up(inc, o); if (lane >= o) inc += u; }
  __shared__ int wsum[4];
  if (lane == 63) wsum[wid] = inc;
  __syncthreads();
  int wbase = 0;
  for (int k = 0; k < wid; ++k) wbase += wsum[k];
  int run = partials[blockIdx.y*64 + blockIdx.x] + wbase + inc - tot;
  #pragma unroll
  for (int j = 0; j < 8; ++j){
    int idx = base + j;
    if (idx < L){
      off[idx] = run;
      run += v[j];
      if (idx == L-1) off[L] = run;
    }
  }
}

// ---------------- place entries into CSR slots: address from PRECOMPUTED rank ----------
// (independent loads -> full MLP; round-5's fused cursor atomic made the scatter address
// depend on an atomic round-trip and serialized at 0.7 TB/s / 150 us)
__global__ __launch_bounds__(256) void place_k(const int* __restrict__ edges, const int* __restrict__ vertex,
                                               const int* __restrict__ e_off, const int* __restrict__ v_off,
                                               const int* __restrict__ re, const int* __restrict__ rv,
                                               int* __restrict__ e_ent, int* __restrict__ v_ent, int nnz){
  int i = blockIdx.x*256 + threadIdx.x;
  if (i < nnz){
    atomicExch(&e_ent[e_off[edges[i]] + re[i]], i);
    atomicExch(&v_ent[v_off[vertex[i]] + rv[i]], i);
  }
}

// ---------------- X0 = X @ W + b  with fused per-node attention scores ----------------
// 64 rows/block, 512 threads. Thread (tr,tc) owns rows {tr*2, tr*2+1} and cols
// {tc*4..tc*4+3} U {64+tc*4..64+tc*4+3}  (consecutive float4 per 16-lane group ->
// conflict-free ds_read_b128; old tc*8 layout was a 4-way bank conflict, 1.33e7/dispatch).
__global__ __launch_bounds__(512) void gemm_k(const float* __restrict__ X, const float* __restrict__ W,
                                              const float* __restrict__ bias, const float* __restrict__ att_e,
                                              float* __restrict__ Y, float* __restrict__ sc_n, int N){
  __shared__ float Bs[64*128];   // k-half x all cols (32 KB)
  __shared__ float As[64*65];    // rows x k-half, +1 pad (16.25 KB)
  __shared__ float att_s[128];
  const int t = threadIdx.x;
  if (t < 128) att_s[t] = att_e[t];
  const int row0 = blockIdx.x * 64;
  const int tr = t >> 4, tc = t & 15;       // tr 0..31, tc 0..15
  const int r = tr*2;
  const int cA = tc*4, cB = 64 + tc*4;
  float acc[2][8];                          // [row][0..3]=cA cols, [4..7]=cB cols
  {
    float4 b0 = ((const float4*)bias)[tc];
    float4 b1 = ((const float4*)bias)[16 + tc];
    acc[0][0]=b0.x; acc[0][1]=b0.y; acc[0][2]=b0.z; acc[0][3]=b0.w;
    acc[0][4]=b1.x; acc[0][5]=b1.y; acc[0][6]=b1.z; acc[0][7]=b1.w;
    #pragma unroll
    for (int j = 0; j < 8; ++j) acc[1][j] = acc[0][j];
  }
  for (int kh = 0; kh < 2; ++kh){
    {
      const float4* W4 = (const float4*)(W + kh*64*128);
      float4* B4 = (float4*)Bs;
      #pragma unroll
      for (int j = 0; j < 4; ++j) B4[j*512 + t] = W4[j*512 + t];
      #pragma unroll
      for (int j = 0; j < 2; ++j){
        int idx = j*512 + t;
        int rr = idx >> 4, c4 = idx & 15;
        int gr = row0 + rr;
        float4 v = make_float4(0.f,0.f,0.f,0.f);
        if (gr < N) v = ((const float4*)X)[(size_t)gr*32 + kh*16 + c4];
        float* dst = &As[rr*65 + c4*4];
        dst[0]=v.x; dst[1]=v.y; dst[2]=v.z; dst[3]=v.w;
      }
    }
    __syncthreads();
    #pragma unroll 4
    for (int k = 0; k < 64; ++k){
      float a0 = As[r*65 + k], a1 = As[(r+1)*65 + k];
      const float4 w0 = *(const float4*)&Bs[k*128 + cA];
      const float4 w1 = *(const float4*)&Bs[k*128 + cB];
      float wv[8] = {w0.x,w0.y,w0.z,w0.w,w1.x,w1.y,w1.z,w1.w};
      #pragma unroll
      for (int j = 0; j < 8; ++j){ acc[0][j] += a0*wv[j]; acc[1][j] += a1*wv[j]; }
    }
    __syncthreads();
  }
  // fused node scores. cols cA..cA+3 belong to head tc>>2; cB cols to head (tc>>2)+4.
  float pA0=0.f, pA1=0.f, pB0=0.f, pB1=0.f;
  #pragma unroll
  for (int j = 0; j < 4; ++j){
    float aa = att_s[cA + j], ab = att_s[cB + j];
    pA0 += acc[0][j]*aa;   pA1 += acc[1][j]*aa;
    pB0 += acc[0][4+j]*ab; pB1 += acc[1][4+j]*ab;
  }
  #pragma unroll
  for (int o = 1; o < 4; o <<= 1){
    pA0 += __shfl_xor(pA0, o); pA1 += __shfl_xor(pA1, o);
    pB0 += __shfl_xor(pB0, o); pB1 += __shfl_xor(pB1, o);
  }
  #pragma unroll
  for (int i = 0; i < 2; ++i){
    int gr = row0 + r + i;
    if (gr < N){
      float4 o0 = make_float4(acc[i][0],acc[i][1],acc[i][2],acc[i][3]);
      float4 o1 = make_float4(acc[i][4],acc[i][5],acc[i][6],acc[i][7]);
      float4* Y4 = (float4*)Y;
      Y4[(size_t)gr*32 + tc]      = o0;
      Y4[(size_t)gr*32 + 16 + tc] = o1;
    }
  }
  if ((tc & 3) == 0){
    int h = tc >> 2;
    int g0 = row0 + r, g1 = row0 + r + 1;
    if (g0 < N){ sc_n[(size_t)g0*8 + h] = leaky(pA0); sc_n[(size_t)g0*8 + 4 + h] = leaky(pB0); }
    if (g1 < N){ sc_n[(size_t)g1*8 + h] = leaky(pA1); sc_n[(size_t)g1*8 + 4 + h] = leaky(pB1); }
  }
}

// ---------------- segment softmax + weighted segment-sum (one wave per segment) --------
// STAGE1: src fp32 (X0), out bf16 (Xe) + relu + fused per-edge scores (fp32, from exact
//         fp32 aggregate -> stage-2 weights are unpolluted by the bf16 value rounding).
// STAGE2: src bf16 (Xe), out fp32 (d_out).
template<bool STAGE1>
__global__ __launch_bounds__(256) void agg_k(const void* __restrict__ src_, const int* __restrict__ map,
                                             const float* __restrict__ sctab, const int* __restrict__ seg_off,
                                             const int* __restrict__ seg_ent, const float* __restrict__ att2,
                                             void* __restrict__ out_, float* __restrict__ sc_out, int nseg){
  __shared__ float s_lds[4][128][8];
  __shared__ int   r_lds[4][128];
  __shared__ float m_lds[4][8];
  __shared__ float d_lds[4][8];
  __shared__ float att_s[128];
  const float* srcf = (const float*)src_;
  const __hip_bfloat16* srcb = (const __hip_bfloat16*)src_;
  const int wid = threadIdx.x >> 6, lane = threadIdx.x & 63;
  if (STAGE1 && threadIdx.x < 128) att_s[threadIdx.x] = att2[threadIdx.x];
  const int seg = blockIdx.x*4 + wid;
  const bool active = seg < nseg;
  int start = 0, cnt = 0;
  if (active){ start = seg_off[seg]; cnt = seg_off[seg+1] - start; }
  const bool fits = (cnt <= 128);

  // phase 1: stage per-entry head scores (gathered from the per-row table) + row ids
  if (active && fits){
    for (int j = lane; j < cnt; j += 64){
      int id = seg_ent[start + j];
      int row = map[id];
      r_lds[wid][j] = row;
      const float4* sp = (const float4*)(sctab + (size_t)row*8);
      float4 x0 = sp[0], x1 = sp[1];
      float* dst = &s_lds[wid][j][0];
      ((float4*)dst)[0] = x0;
      ((float4*)dst)[1] = x1;
    }
  }
  __syncthreads();
  // phase 2: wave-parallel per-head max & sum. lane = jj*8 + h
  if (active && fits){
    const int h = lane & 7, jj = lane >> 3;
    float m = -INFINITY;
    for (int j = jj; j < cnt; j += 8) m = fmaxf(m, s_lds[wid][j][h]);
    #pragma unroll
    for (int o = 8; o < 64; o <<= 1) m = fmaxf(m, __shfl_xor(m, o));
    float s = 0.f;
    for (int j = jj; j < cnt; j += 8) s += __expf(s_lds[wid][j][h] - m);
    #pragma unroll
    for (int o = 8; o < 64; o <<= 1) s += __shfl_xor(s, o);
    if (lane < 8){ m_lds[wid][lane] = m; d_lds[wid][lane] = 1.f / (s + 1e-16f); }
  }
  __syncthreads();
  // phase 2b: scores -> softmax weights in place
  if (active && fits){
    for (int idx = lane; idx < cnt*8; idx += 64){
      int j = idx >> 3, h = idx & 7;
      s_lds[wid][j][h] = __expf(s_lds[wid][j][h] - m_lds[wid][h]) * d_lds[wid][h];
    }
  }
  __syncthreads();
  // phase 3: weighted sum of gathered rows; lane covers cols (lane, lane+64)
  if (active){
    float acc0 = 0.f, acc1 = 0.f;
    const int ha = lane >> 4, hb = ha + 4;
    if (fits){
      for (int j = 0; j < cnt; ++j){
        float wa = s_lds[wid][j][ha];
        float wb = s_lds[wid][j][hb];
        float x0, x1;
        if (STAGE1){
          const float* xr = srcf + (size_t)r_lds[wid][j]*128;
          x0 = xr[lane]; x1 = xr[lane + 64];
        } else {
          const __hip_bfloat16* xr = srcb + (size_t)r_lds[wid][j]*128;
          x0 = __bfloat162float(xr[lane]); x1 = __bfloat162float(xr[lane + 64]);
        }
        acc0 += wa * x0;
        acc1 += wb * x1;
      }
    } else {
      // overflow fallback (cnt > 128): 3-pass from global; essentially never taken
      float ma = -INFINITY, mb = -INFINITY;
      for (int j = 0; j < cnt; ++j){
        int id = seg_ent[start + j];
        int row = map[id];
        ma = fmaxf(ma, sctab[(size_t)row*8 + ha]);
        mb = fmaxf(mb, sctab[(size_t)row*8 + hb]);
      }
      float sa = 0.f, sb = 0.f;
      for (int j = 0; j < cnt; ++j){
        int id = seg_ent[start + j];
        int row = map[id];
        sa += __expf(sctab[(size_t)row*8 + ha] - ma);
        sb += __expf(sctab[(size_t)row*8 + hb] - mb);
      }
      float ra = 1.f/(sa + 1e-16f), rb = 1.f/(sb + 1e-16f);
      for (int j = 0; j < cnt; ++j){
        int id = seg_ent[start + j];
        int row = map[id];
        float wa = __expf(sctab[(size_t)row*8 + ha] - ma) * ra;
        float wb = __expf(sctab[(size_t)row*8 + hb] - mb) * rb;
        float x0, x1;
        if (STAGE1){
          const float* xr = srcf + (size_t)row*128;
          x0 = xr[lane]; x1 = xr[lane + 64];
        } else {
          const __hip_bfloat16* xr = srcb + (size_t)row*128;
          x0 = __bfloat162float(xr[lane]); x1 = __bfloat162float(xr[lane + 64]);
        }
        acc0 += wa * x0;
        acc1 += wb * x1;
      }
    }
    if (STAGE1){
      float o0 = fmaxf(acc0, 0.f);
      float o1 = fmaxf(acc1, 0.f);
      __hip_bfloat16* outb = (__hip_bfloat16*)out_;
      outb[(size_t)seg*128 + lane]      = __float2bfloat16(o0);
      outb[(size_t)seg*128 + 64 + lane] = __float2bfloat16(o1);
      // fused per-segment (edge) scores for stage 2, from the EXACT fp32 aggregate
      float p0 = o0 * att_s[lane];        // att2[ha*16 + (lane&15)] == att2[lane]
      float p1 = o1 * att_s[lane + 64];   // att2[(ha+4)*16 + (lane&15)] == att2[lane+64]
      #pragma unroll
      for (int o = 1; o < 16; o <<= 1){ p0 += __shfl_xor(p0, o); p1 += __shfl_xor(p1, o); }
      if ((lane & 15) == 0){
        sc_out[(size_t)seg*8 + (lane >> 4)]     = leaky(p0);
        sc_out[(size_t)seg*8 + 4 + (lane >> 4)] = leaky(p1);
      }
    } else {
      float* outf = (float*)out_;
      outf[(size_t)seg*128 + lane]      = acc0;
      outf[(size_t)seg*128 + 64 + lane] = acc1;
    }
  }
}

extern "C" void kernel_launch(void* const* d_in, const int* in_sizes, int n_in,
                              void* d_out, int out_size, void* d_ws, size_t ws_size,
                              hipStream_t stream){
  const float* X      = (const float*)d_in[0];
  const int*   vertex = (const int*)d_in[1];
  const int*   edges  = (const int*)d_in[2];
  const float* W_w    = (const float*)d_in[3];
  const float* W_b    = (const float*)d_in[4];
  const float* att_e  = (const float*)d_in[5];
  const float* att_v  = (const float*)d_in[6];
  const int N   = in_sizes[0] / 128;   // 100000
  const int NNZ = in_sizes[1];         // 800000
  const int M   = 50000;               // edge_num (fixed problem size)

  char* p = (char*)d_ws;
  auto take = [&](size_t bytes)->void*{
    void* q = (void*)p;
    p += (bytes + 255) & ~(size_t)255;
    return q;
  };
  float* X0        = (float*)take((size_t)N*128*sizeof(float));          // 51.2 MB
  __hip_bfloat16* Xe = (__hip_bfloat16*)take((size_t)M*128*sizeof(__hip_bfloat16)); // 12.8 MB
  float* sc_n      = (float*)take((size_t)N*8*sizeof(float));            // 3.2 MB
  float* sc_e      = (float*)take((size_t)M*8*sizeof(float));            // 1.6 MB
  int*   e_off     = (int*)take((size_t)(M+1)*sizeof(int));
  int*   v_off     = (int*)take((size_t)(N+1)*sizeof(int));
  int*   e_cnt     = (int*)take((size_t)M*sizeof(int));
  int*   v_cnt     = (int*)take((size_t)N*sizeof(int));
  int*   re        = (int*)take((size_t)NNZ*sizeof(int));
  int*   rv        = (int*)take((size_t)NNZ*sizeof(int));
  int*   e_ent     = (int*)take((size_t)NNZ*sizeof(int));
  int*   v_ent     = (int*)take((size_t)NNZ*sizeof(int));
  int*   partials  = (int*)take(128*sizeof(int));

  hipMemsetAsync(e_cnt, 0, (size_t)M*sizeof(int), stream);
  hipMemsetAsync(v_cnt, 0, (size_t)N*sizeof(int), stream);

  gemm_k<<<dim3((N+63)/64), 512, 0, stream>>>(X, W_w, W_b, att_e, X0, sc_n, N);

  hist_rank_k<<<dim3((NNZ+255)/256), 256, 0, stream>>>(edges, vertex, e_cnt, v_cnt, re, rv, NNZ);
  const int LMAX = (N > M) ? N : M;
  const int nb = (LMAX + 2047)/2048;        // <= 64
  scan_reduce_k<<<dim3(nb,2), 256, 0, stream>>>(e_cnt, v_cnt, M, N, partials);
  scan_partials_k<<<dim3(1), 128, 0, stream>>>(partials);
  scan_write_k<<<dim3(nb,2), 256, 0, stream>>>(e_cnt, v_cnt, M, N, partials, e_off, v_off);
  place_k<<<dim3((NNZ+255)/256), 256, 0, stream>>>(edges, vertex, e_off, v_off, re, rv, e_ent, v_ent, NNZ);

  // stage 1: per-hyperedge attention (+ fused edge scores for stage 2, bf16 Xe out)
  agg_k<true><<<dim3((M+3)/4), 256, 0, stream>>>(X0, vertex, sc_n, e_off, e_ent, att_v, Xe, sc_e, M);

  // stage 2: per-vertex attention (bf16 Xe gather, fp32 out)
  agg_k<false><<<dim3((N+3)/4), 256, 0, stream>>>(Xe, edges, sc_e, v_off, v_ent, nullptr, d_out, nullptr, N);
}

// Round 9
// 454.699 us; speedup vs baseline: 1.2718x; 1.0922x over previous
//
#include <hip/hip_runtime.h>
#include <hip/hip_bf16.h>
#include <cstdint>
#include <cmath>

#define NEG_SLOPE 0.2f

static __device__ __forceinline__ float leaky(float x){ return x >= 0.f ? x : NEG_SLOPE*x; }
static __device__ __forceinline__ unsigned short bf16bits(float x){
  __hip_bfloat16 h = __float2bfloat16(x);           // RNE
  return *reinterpret_cast<unsigned short*>(&h);
}
static __device__ __forceinline__ float bfbits2f(unsigned short u){
  unsigned v = ((unsigned)u) << 16;                  // bf16->f32 is exact
  return __uint_as_float(v);
}

// ---------------- histogram + rank (rank = arrival order within segment) ----------------
__global__ __launch_bounds__(256) void hist_rank_k(const int* __restrict__ edges, const int* __restrict__ vertex,
                                                   int* __restrict__ ce, int* __restrict__ cv,
                                                   int* __restrict__ re, int* __restrict__ rv, int nnz){
  int i = blockIdx.x*256 + threadIdx.x;
  if (i < nnz){
    re[i] = atomicAdd(&ce[edges[i]], 1);
    rv[i] = atomicAdd(&cv[vertex[i]], 1);
  }
}

// ---------------- 3-pass exclusive scan (both arrays via blockIdx.y) ----------------
__global__ __launch_bounds__(256) void scan_reduce_k(const int* __restrict__ ce, const int* __restrict__ cv,
                                                     int M, int N, int* __restrict__ partials){
  const int* src = blockIdx.y ? cv : ce;
  const int L = blockIdx.y ? N : M;
  const int base = blockIdx.x*2048;
  int s = 0;
  for (int j = threadIdx.x; j < 2048; j += 256){
    int idx = base + j;
    if (idx < L) s += src[idx];
  }
  for (int o = 32; o > 0; o >>= 1) s += __shfl_down(s, o);
  __shared__ int wsum[4];
  if ((threadIdx.x & 63) == 0) wsum[threadIdx.x >> 6] = s;
  __syncthreads();
  if (threadIdx.x == 0) partials[blockIdx.y*64 + blockIdx.x] = wsum[0]+wsum[1]+wsum[2]+wsum[3];
}

__global__ __launch_bounds__(128) void scan_partials_k(int* __restrict__ partials){
  const int w = threadIdx.x >> 6, l = threadIdx.x & 63;
  int v = partials[w*64 + l];
  int inc = v;
  for (int o = 1; o < 64; o <<= 1){ int u = __shfl_up(inc, o); if (l >= o) inc += u; }
  partials[w*64 + l] = inc - v;   // exclusive
}

__global__ __launch_bounds__(256) void scan_write_k(const int* __restrict__ ce, const int* __restrict__ cv,
                                                    int M, int N, const int* __restrict__ partials,
                                                    int* __restrict__ e_off, int* __restrict__ v_off){
  const int* src; int L; int* off;
  if (blockIdx.y == 0){ src = ce; L = M; off = e_off; }
  else                { src = cv; L = N; off = v_off; }
  const int base = blockIdx.x*2048 + threadIdx.x*8;
  int v[8];
  int tot = 0;
  #pragma unroll
  for (int j = 0; j < 8; ++j){ int idx = base+j; v[j] = (idx < L) ? src[idx] : 0; tot += v[j]; }
  const int lane = threadIdx.x & 63, wid = threadIdx.x >> 6;
  int inc = tot;
  for (int o = 1; o < 64; o <<= 1){ int u = __shfl_up(inc, o); if (lane >= o) inc += u; }
  __shared__ int wsum[4];
  if (lane == 63) wsum[wid] = inc;
  __syncthreads();
  int wbase = 0;
  for (int k = 0; k < wid; ++k) wbase += wsum[k];
  int run = partials[blockIdx.y*64 + blockIdx.x] + wbase + inc - tot;
  #pragma unroll
  for (int j = 0; j < 8; ++j){
    int idx = base + j;
    if (idx < L){
      off[idx] = run;
      run += v[j];
      if (idx == L-1) off[L] = run;
    }
  }
}

// ---------------- place ROW IDS into CSR slots (address from precomputed rank) ---------
// Stores the source-row id directly (vertex id for the edge-CSR, edge id for the
// vertex-CSR) so agg_k needs no map[] indirection.
__global__ __launch_bounds__(256) void place_k(const int* __restrict__ edges, const int* __restrict__ vertex,
                                               const int* __restrict__ e_off, const int* __restrict__ v_off,
                                               const int* __restrict__ re, const int* __restrict__ rv,
                                               int* __restrict__ e_rows, int* __restrict__ v_rows, int nnz){
  int i = blockIdx.x*256 + threadIdx.x;
  if (i < nnz){
    int e = edges[i], v = vertex[i];
    atomicExch(&e_rows[e_off[e] + re[i]], v);
    atomicExch(&v_rows[v_off[v] + rv[i]], e);
  }
}

// ---------------- X0 = X @ W + b -> bf16, with fused per-node attention scores --------
// Scores computed from EXACT fp32 accumulators; only the stored values are rounded.
__global__ __launch_bounds__(512) void gemm_k(const float* __restrict__ X, const float* __restrict__ W,
                                              const float* __restrict__ bias, const float* __restrict__ att_e,
                                              __hip_bfloat16* __restrict__ Y, float* __restrict__ sc_n, int N){
  __shared__ float Bs[64*128];   // k-half x all cols (32 KB)
  __shared__ float As[64*65];    // rows x k-half, +1 pad (16.25 KB)
  __shared__ float att_s[128];
  const int t = threadIdx.x;
  if (t < 128) att_s[t] = att_e[t];
  const int row0 = blockIdx.x * 64;
  const int tr = t >> 4, tc = t & 15;       // tr 0..31, tc 0..15
  const int r = tr*2;
  const int cA = tc*4, cB = 64 + tc*4;      // conflict-free ds_read_b128 column map
  float acc[2][8];
  {
    float4 b0 = ((const float4*)bias)[tc];
    float4 b1 = ((const float4*)bias)[16 + tc];
    acc[0][0]=b0.x; acc[0][1]=b0.y; acc[0][2]=b0.z; acc[0][3]=b0.w;
    acc[0][4]=b1.x; acc[0][5]=b1.y; acc[0][6]=b1.z; acc[0][7]=b1.w;
    #pragma unroll
    for (int j = 0; j < 8; ++j) acc[1][j] = acc[0][j];
  }
  for (int kh = 0; kh < 2; ++kh){
    {
      const float4* W4 = (const float4*)(W + kh*64*128);
      float4* B4 = (float4*)Bs;
      #pragma unroll
      for (int j = 0; j < 4; ++j) B4[j*512 + t] = W4[j*512 + t];
      #pragma unroll
      for (int j = 0; j < 2; ++j){
        int idx = j*512 + t;
        int rr = idx >> 4, c4 = idx & 15;
        int gr = row0 + rr;
        float4 v = make_float4(0.f,0.f,0.f,0.f);
        if (gr < N) v = ((const float4*)X)[(size_t)gr*32 + kh*16 + c4];
        float* dst = &As[rr*65 + c4*4];
        dst[0]=v.x; dst[1]=v.y; dst[2]=v.z; dst[3]=v.w;
      }
    }
    __syncthreads();
    #pragma unroll 4
    for (int k = 0; k < 64; ++k){
      float a0 = As[r*65 + k], a1 = As[(r+1)*65 + k];
      const float4 w0 = *(const float4*)&Bs[k*128 + cA];
      const float4 w1 = *(const float4*)&Bs[k*128 + cB];
      float wv[8] = {w0.x,w0.y,w0.z,w0.w,w1.x,w1.y,w1.z,w1.w};
      #pragma unroll
      for (int j = 0; j < 8; ++j){ acc[0][j] += a0*wv[j]; acc[1][j] += a1*wv[j]; }
    }
    __syncthreads();
  }
  // fused node scores. cols cA..cA+3 -> head tc>>2; cB cols -> head (tc>>2)+4.
  float pA0=0.f, pA1=0.f, pB0=0.f, pB1=0.f;
  #pragma unroll
  for (int j = 0; j < 4; ++j){
    float aa = att_s[cA + j], ab = att_s[cB + j];
    pA0 += acc[0][j]*aa;   pA1 += acc[1][j]*aa;
    pB0 += acc[0][4+j]*ab; pB1 += acc[1][4+j]*ab;
  }
  #pragma unroll
  for (int o = 1; o < 4; o <<= 1){
    pA0 += __shfl_xor(pA0, o); pA1 += __shfl_xor(pA1, o);
    pB0 += __shfl_xor(pB0, o); pB1 += __shfl_xor(pB1, o);
  }
  #pragma unroll
  for (int i = 0; i < 2; ++i){
    int gr = row0 + r + i;
    if (gr < N){
      ushort4 s0 = make_ushort4(bf16bits(acc[i][0]), bf16bits(acc[i][1]),
                                bf16bits(acc[i][2]), bf16bits(acc[i][3]));
      ushort4 s1 = make_ushort4(bf16bits(acc[i][4]), bf16bits(acc[i][5]),
                                bf16bits(acc[i][6]), bf16bits(acc[i][7]));
      *(ushort4*)((unsigned short*)Y + (size_t)gr*128 + cA) = s0;
      *(ushort4*)((unsigned short*)Y + (size_t)gr*128 + cB) = s1;
    }
  }
  if ((tc & 3) == 0){
    int h = tc >> 2;
    int g0 = row0 + r, g1 = row0 + r + 1;
    if (g0 < N){ sc_n[(size_t)g0*8 + h] = leaky(pA0); sc_n[(size_t)g0*8 + 4 + h] = leaky(pB0); }
    if (g1 < N){ sc_n[(size_t)g1*8 + h] = leaky(pA1); sc_n[(size_t)g1*8 + 4 + h] = leaky(pB1); }
  }
}

// ---------------- segment softmax + weighted segment-sum (one wave per segment) --------
// src is bf16 in BOTH stages (X0 bf16 / Xe bf16). Lane owns cols {2l, 2l+1} (same head).
// STAGE1: out bf16 Xe + relu + fused per-edge scores. STAGE2: out fp32 d_out.
template<bool STAGE1>
__global__ __launch_bounds__(256) void agg_k(const __hip_bfloat16* __restrict__ src,
                                             const float* __restrict__ sctab, const int* __restrict__ seg_off,
                                             const int* __restrict__ seg_rows, const float* __restrict__ att2,
                                             void* __restrict__ out_, float* __restrict__ sc_out, int nseg){
  __shared__ float s_lds[4][128][8];
  __shared__ int   r_lds[4][128];
  __shared__ float m_lds[4][8];
  __shared__ float d_lds[4][8];
  __shared__ float att_s[128];
  const unsigned short* srcu = (const unsigned short*)src;
  const int wid = threadIdx.x >> 6, lane = threadIdx.x & 63;
  if (STAGE1 && threadIdx.x < 128) att_s[threadIdx.x] = att2[threadIdx.x];
  const int seg = blockIdx.x*4 + wid;
  const bool active = seg < nseg;
  int start = 0, cnt = 0;
  if (active){ start = seg_off[seg]; cnt = seg_off[seg+1] - start; }
  const bool fits = (cnt <= 128);

  // phase 1: stage per-entry head scores (gathered from per-row table) + row ids
  if (active && fits){
    for (int j = lane; j < cnt; j += 64){
      int row = seg_rows[start + j];
      r_lds[wid][j] = row;
      const float4* sp = (const float4*)(sctab + (size_t)row*8);
      float4 x0 = sp[0], x1 = sp[1];
      float* dst = &s_lds[wid][j][0];
      ((float4*)dst)[0] = x0;
      ((float4*)dst)[1] = x1;
    }
  }
  __syncthreads();
  // phase 2: wave-parallel per-head max & sum. lane = jj*8 + h
  if (active && fits){
    const int h = lane & 7, jj = lane >> 3;
    float m = -INFINITY;
    for (int j = jj; j < cnt; j += 8) m = fmaxf(m, s_lds[wid][j][h]);
    #pragma unroll
    for (int o = 8; o < 64; o <<= 1) m = fmaxf(m, __shfl_xor(m, o));
    float s = 0.f;
    for (int j = jj; j < cnt; j += 8) s += __expf(s_lds[wid][j][h] - m);
    #pragma unroll
    for (int o = 8; o < 64; o <<= 1) s += __shfl_xor(s, o);
    if (lane < 8){ m_lds[wid][lane] = m; d_lds[wid][lane] = 1.f / (s + 1e-16f); }
  }
  __syncthreads();
  // phase 2b: scores -> softmax weights in place
  if (active && fits){
    for (int idx = lane; idx < cnt*8; idx += 64){
      int j = idx >> 3, h = idx & 7;
      s_lds[wid][j][h] = __expf(s_lds[wid][j][h] - m_lds[wid][h]) * d_lds[wid][h];
    }
  }
  __syncthreads();
  // phase 3: weighted sum of gathered rows; lane covers cols {2l, 2l+1} (head l>>3)
  if (active){
    float acc0 = 0.f, acc1 = 0.f;
    const int h2 = lane >> 3;
    const int c2 = lane*2;
    if (fits){
      for (int j = 0; j < cnt; ++j){
        float w = s_lds[wid][j][h2];
        ushort2 u = *(const ushort2*)(srcu + (size_t)r_lds[wid][j]*128 + c2);
        acc0 += w * bfbits2f(u.x);
        acc1 += w * bfbits2f(u.y);
      }
    } else {
      // overflow fallback (cnt > 128): 3-pass from global; essentially never taken
      float m = -INFINITY;
      for (int j = 0; j < cnt; ++j){
        int row = seg_rows[start + j];
        m = fmaxf(m, sctab[(size_t)row*8 + h2]);
      }
      float s = 0.f;
      for (int j = 0; j < cnt; ++j){
        int row = seg_rows[start + j];
        s += __expf(sctab[(size_t)row*8 + h2] - m);
      }
      float rs = 1.f/(s + 1e-16f);
      for (int j = 0; j < cnt; ++j){
        int row = seg_rows[start + j];
        float w = __expf(sctab[(size_t)row*8 + h2] - m) * rs;
        ushort2 u = *(const ushort2*)(srcu + (size_t)row*128 + c2);
        acc0 += w * bfbits2f(u.x);
        acc1 += w * bfbits2f(u.y);
      }
    }
    if (STAGE1){
      float o0 = fmaxf(acc0, 0.f);
      float o1 = fmaxf(acc1, 0.f);
      ushort2 uo = make_ushort2(bf16bits(o0), bf16bits(o1));
      *(ushort2*)((unsigned short*)out_ + (size_t)seg*128 + c2) = uo;
      // fused per-segment (edge) scores for stage 2, from the EXACT fp32 aggregate
      float p = o0 * att_s[c2] + o1 * att_s[c2 + 1];   // att flat idx of col c is c
      p += __shfl_xor(p, 1); p += __shfl_xor(p, 2); p += __shfl_xor(p, 4);
      if ((lane & 7) == 0) sc_out[(size_t)seg*8 + h2] = leaky(p);
    } else {
      *(float2*)((float*)out_ + (size_t)seg*128 + c2) = make_float2(acc0, acc1);
    }
  }
}

extern "C" void kernel_launch(void* const* d_in, const int* in_sizes, int n_in,
                              void* d_out, int out_size, void* d_ws, size_t ws_size,
                              hipStream_t stream){
  const float* X      = (const float*)d_in[0];
  const int*   vertex = (const int*)d_in[1];
  const int*   edges  = (const int*)d_in[2];
  const float* W_w    = (const float*)d_in[3];
  const float* W_b    = (const float*)d_in[4];
  const float* att_e  = (const float*)d_in[5];
  const float* att_v  = (const float*)d_in[6];
  const int N   = in_sizes[0] / 128;   // 100000
  const int NNZ = in_sizes[1];         // 800000
  const int M   = 50000;               // edge_num (fixed problem size)

  char* p = (char*)d_ws;
  auto take = [&](size_t bytes)->void*{
    void* q = (void*)p;
    p += (bytes + 255) & ~(size_t)255;
    return q;
  };
  __hip_bfloat16* X0 = (__hip_bfloat16*)take((size_t)N*128*sizeof(__hip_bfloat16)); // 25.6 MB
  __hip_bfloat16* Xe = (__hip_bfloat16*)take((size_t)M*128*sizeof(__hip_bfloat16)); // 12.8 MB
  float* sc_n      = (float*)take((size_t)N*8*sizeof(float));            // 3.2 MB
  float* sc_e      = (float*)take((size_t)M*8*sizeof(float));            // 1.6 MB
  int*   e_off     = (int*)take((size_t)(M+1)*sizeof(int));
  int*   v_off     = (int*)take((size_t)(N+1)*sizeof(int));
  int*   e_cnt     = (int*)take((size_t)M*sizeof(int));
  int*   v_cnt     = (int*)take((size_t)N*sizeof(int));
  int*   re        = (int*)take((size_t)NNZ*sizeof(int));
  int*   rv        = (int*)take((size_t)NNZ*sizeof(int));
  int*   e_rows    = (int*)take((size_t)NNZ*sizeof(int));
  int*   v_rows    = (int*)take((size_t)NNZ*sizeof(int));
  int*   partials  = (int*)take(128*sizeof(int));

  hipMemsetAsync(e_cnt, 0, (size_t)M*sizeof(int), stream);
  hipMemsetAsync(v_cnt, 0, (size_t)N*sizeof(int), stream);

  gemm_k<<<dim3((N+63)/64), 512, 0, stream>>>(X, W_w, W_b, att_e, X0, sc_n, N);

  hist_rank_k<<<dim3((NNZ+255)/256), 256, 0, stream>>>(edges, vertex, e_cnt, v_cnt, re, rv, NNZ);
  const int LMAX = (N > M) ? N : M;
  const int nb = (LMAX + 2047)/2048;        // <= 64
  scan_reduce_k<<<dim3(nb,2), 256, 0, stream>>>(e_cnt, v_cnt, M, N, partials);
  scan_partials_k<<<dim3(1), 128, 0, stream>>>(partials);
  scan_write_k<<<dim3(nb,2), 256, 0, stream>>>(e_cnt, v_cnt, M, N, partials, e_off, v_off);
  place_k<<<dim3((NNZ+255)/256), 256, 0, stream>>>(edges, vertex, e_off, v_off, re, rv, e_rows, v_rows, NNZ);

  // stage 1: per-hyperedge attention (bf16 X0 gather -> bf16 Xe + fused edge scores)
  agg_k<true><<<dim3((M+3)/4), 256, 0, stream>>>(X0, sc_n, e_off, e_rows, att_v, Xe, sc_e, M);

  // stage 2: per-vertex attention (bf16 Xe gather -> fp32 out)
  agg_k<false><<<dim3((N+3)/4), 256, 0, stream>>>(Xe, sc_e, v_off, v_rows, nullptr, d_out, nullptr, N);
}